// Round 5
// baseline (405.049 us; speedup 1.0000x reference)
//
#include <hip/hip_runtime.h>
#include <hip/hip_bf16.h>

// Problem constants (reference: B=2, N=2048, DIM=1024, INTER=1024, HEAD=16, N_SEG=4)
#define BB 2
#define NN 2048
#define DIM 1024
#define INTER 1024
#define NHEAD 16
#define HDIM 64          // INTER / NHEAD
#define NSEG 4
#define QKVW (3 * INTER) // 3072

typedef __attribute__((ext_vector_type(8))) short bf16x8;
typedef __attribute__((ext_vector_type(4))) float f32x4;

static __device__ __forceinline__ unsigned short f2bf(float f) {
    __hip_bfloat16 h = __float2bfloat16(f);   // RNE
    return *reinterpret_cast<unsigned short*>(&h);
}

// ---------------------------------------------------------------------------
// Prepass: fp32 -> bf16 elementwise (features).
// ---------------------------------------------------------------------------
__global__ __launch_bounds__(256) void conv_f32_bf16(const float* __restrict__ in,
                                                     unsigned short* __restrict__ out) {
    int i = (blockIdx.x * 256 + threadIdx.x) * 4;
    float4 v = *(const float4*)&in[i];
    ushort4 o = {f2bf(v.x), f2bf(v.y), f2bf(v.z), f2bf(v.w)};
    *(ushort4*)&out[i] = o;
}

// ---------------------------------------------------------------------------
// Prepass: mask int32 -> int8 (4x less global traffic; attention stages it
// with a single 16B/thread global_load_lds instead of 4 int4 loads + pack).
// ---------------------------------------------------------------------------
__global__ __launch_bounds__(256) void conv_mask_i8(const int* __restrict__ in,
                                                    unsigned char* __restrict__ out) {
    int i = (blockIdx.x * 256 + threadIdx.x) * 16;
    unsigned char r[16];
#pragma unroll
    for (int c = 0; c < 4; ++c) {
        int4 v = *(const int4*)&in[i + c * 4];
        r[c * 4 + 0] = (unsigned char)(v.x & 3);
        r[c * 4 + 1] = (unsigned char)(v.y & 3);
        r[c * 4 + 2] = (unsigned char)(v.z & 3);
        r[c * 4 + 3] = (unsigned char)(v.w & 3);
    }
    *(int4*)&out[i] = *(const int4*)r;
}

// ---------------------------------------------------------------------------
// Prepass: convert + transpose  in[R][C] fp32  ->  out[C][R] bf16.
// ---------------------------------------------------------------------------
__global__ __launch_bounds__(256) void transp_f32_bf16(const float* __restrict__ in,
                                                       unsigned short* __restrict__ out,
                                                       int R, int C) {
    __shared__ float tile[64][65];
    const int r0 = blockIdx.y * 64, c0 = blockIdx.x * 64;
    const int t = threadIdx.x;
#pragma unroll
    for (int it = 0; it < 4; ++it) {
        int r = it * 16 + (t >> 4);
        int c = (t & 15) * 4;
        float4 v = *(const float4*)&in[(size_t)(r0 + r) * C + c0 + c];
        tile[r][c] = v.x; tile[r][c + 1] = v.y; tile[r][c + 2] = v.z; tile[r][c + 3] = v.w;
    }
    __syncthreads();
#pragma unroll
    for (int it = 0; it < 4; ++it) {
        int c = it * 16 + (t >> 4);
        int r = (t & 15) * 4;
        ushort4 o = {f2bf(tile[r][c]), f2bf(tile[r + 1][c]), f2bf(tile[r + 2][c]), f2bf(tile[r + 3][c])};
        *(ushort4*)&out[(size_t)(c0 + c) * R + r0 + r] = o;
    }
}

// ---------------------------------------------------------------------------
// QKV GEMM, bf16 MFMA (m97 structure): [4096][1024] @ [3072][1024]^T.
// q|k -> Cqk [4096][2048]; v -> Vtg transposed [b][h*64+d][n].
// ---------------------------------------------------------------------------
#define GBK 32

__global__ __launch_bounds__(256) void gemm_qkv_mfma(
        const unsigned short* __restrict__ A,    // [4096][1024] bf16
        const unsigned short* __restrict__ Bt,   // [3072][1024] bf16
        unsigned short* __restrict__ Cqk,        // [4096][2048] bf16 (q|k)
        unsigned short* __restrict__ Vtg) {      // [2][1024][2048] bf16
    const int K = 1024;
    __shared__ __align__(16) unsigned short As[128][GBK];
    __shared__ __align__(16) unsigned short Bs[128][GBK];
    const int t = threadIdx.x;
    const int w = t >> 6, lane = t & 63, l15 = lane & 15, quad = lane >> 4;
    const int wr = w >> 1, wc = w & 1;
    const int row0 = blockIdx.y * 128, col0 = blockIdx.x * 128;
    const int lrow = lane >> 2;
    const int lkof = (lane & 3) * 8;

    f32x4 acc[4][4];
#pragma unroll
    for (int i = 0; i < 4; ++i)
#pragma unroll
        for (int j = 0; j < 4; ++j) acc[i][j] = (f32x4){0.f, 0.f, 0.f, 0.f};

    for (int k0 = 0; k0 < K; k0 += GBK) {
#pragma unroll
        for (int c = 0; c < 2; ++c) {
            int rbase = w * 32 + c * 16;
            const unsigned short* ga = A  + (size_t)(row0 + rbase + lrow) * K + k0 + lkof;
            const unsigned short* gb = Bt + (size_t)(col0 + rbase + lrow) * K + k0 + lkof;
            __builtin_amdgcn_global_load_lds(
                (const __attribute__((address_space(1))) void*)ga,
                (__attribute__((address_space(3))) void*)&As[rbase][0], 16, 0, 0);
            __builtin_amdgcn_global_load_lds(
                (const __attribute__((address_space(1))) void*)gb,
                (__attribute__((address_space(3))) void*)&Bs[rbase][0], 16, 0, 0);
        }
        __syncthreads();
        bf16x8 af[4], bfr[4];
#pragma unroll
        for (int i = 0; i < 4; ++i) af[i]  = *(const bf16x8*)&As[wr * 64 + i * 16 + l15][quad * 8];
#pragma unroll
        for (int j = 0; j < 4; ++j) bfr[j] = *(const bf16x8*)&Bs[wc * 64 + j * 16 + l15][quad * 8];
#pragma unroll
        for (int i = 0; i < 4; ++i)
#pragma unroll
            for (int j = 0; j < 4; ++j)
                acc[i][j] = __builtin_amdgcn_mfma_f32_16x16x32_bf16(af[i], bfr[j], acc[i][j], 0, 0, 0);
        __syncthreads();
    }

    if (col0 < 2048) {
#pragma unroll
        for (int i = 0; i < 4; ++i)
#pragma unroll
            for (int j = 0; j < 4; ++j)
#pragma unroll
                for (int r = 0; r < 4; ++r) {
                    int row = row0 + wr * 64 + i * 16 + quad * 4 + r;
                    int col = col0 + wc * 64 + j * 16 + l15;
                    Cqk[(size_t)row * 2048 + col] = f2bf(acc[i][j][r]);
                }
    } else {
#pragma unroll
        for (int i = 0; i < 4; ++i)
#pragma unroll
            for (int j = 0; j < 4; ++j) {
                int col = col0 + wc * 64 + j * 16 + l15 - 2048;   // h*64+d
                int row = row0 + wr * 64 + i * 16 + quad * 4;     // b*2048+n
                int bb = row >> 11, n = row & 2047;
                ushort4 o = {f2bf(acc[i][j][0]), f2bf(acc[i][j][1]),
                             f2bf(acc[i][j][2]), f2bf(acc[i][j][3])};
                *(ushort4*)&Vtg[((size_t)bb * INTER + col) * NN + n] = o;
            }
    }
}

// ---------------------------------------------------------------------------
// Tiled fp32 GEMM (out-projection): measured 131 TF = 83% of vector peak.
// ---------------------------------------------------------------------------
#define TILE 64
#define BK 16

__global__ __launch_bounds__(256) void gemm_fp32(const float* __restrict__ A,
                                                 const float* __restrict__ B,
                                                 float* __restrict__ C,
                                                 int M, int N, int K) {
    __shared__ float As[BK][TILE + 4];
    __shared__ float Bs[BK][TILE + 4];
    const int t  = threadIdx.x;
    const int tx = t & 15;
    const int ty = t >> 4;
    const int row0 = blockIdx.y * TILE;
    const int col0 = blockIdx.x * TILE;
    const int arow = t >> 2;
    const int akq  = (t & 3) * 4;
    const int brow = t >> 4;
    const int bcol = (t & 15) * 4;
    float acc[4][4] = {};
    for (int k0 = 0; k0 < K; k0 += BK) {
        float4 av = *(const float4*)&A[(size_t)(row0 + arow) * K + k0 + akq];
        float4 bv = *(const float4*)&B[(size_t)(k0 + brow) * N + col0 + bcol];
        As[akq + 0][arow] = av.x;
        As[akq + 1][arow] = av.y;
        As[akq + 2][arow] = av.z;
        As[akq + 3][arow] = av.w;
        *(float4*)&Bs[brow][bcol] = bv;
        __syncthreads();
#pragma unroll
        for (int kk = 0; kk < BK; ++kk) {
            float4 a4 = *(const float4*)&As[kk][ty * 4];
            float4 b4 = *(const float4*)&Bs[kk][tx * 4];
            float a[4] = {a4.x, a4.y, a4.z, a4.w};
            float b[4] = {b4.x, b4.y, b4.z, b4.w};
#pragma unroll
            for (int i = 0; i < 4; ++i)
#pragma unroll
                for (int j = 0; j < 4; ++j)
                    acc[i][j] += a[i] * b[j];
        }
        __syncthreads();
    }
#pragma unroll
    for (int i = 0; i < 4; ++i) {
        float4 o = {acc[i][0], acc[i][1], acc[i][2], acc[i][3]};
        *(float4*)&C[(size_t)(row0 + ty * 4 + i) * N + col0 + tx * 4] = o;
    }
}

// ---------------------------------------------------------------------------
// Segment-masked attention, MFMA bf16, single sweep over keys.
// Round-5: async global_load_lds staging (K/V/mask; width=16, double-buffered,
// one barrier/tile) + XOR-swizzled pad-free LDS (stride 64, 16B granule
// g ^= row&7 -> all b128 reads 2-way = free) -> 48 KB LDS -> 3 blocks/CU.
// Math identical to rounds 2-4 (verified absmax 9.8e-4).
// ---------------------------------------------------------------------------
__global__ __launch_bounds__(256, 3) void attn_seg_mfma(
        const unsigned short* __restrict__ qk,    // bf16 [4096][2048] = q|k
        const unsigned short* __restrict__ vtg,   // bf16 [2][1024][2048]
        const unsigned char* __restrict__ mask8,  // [B,N,N] int8 seg ids
        float* __restrict__ ctx) {                // [4096][1024]
    __shared__ __align__(16) unsigned short Ks[2][64][64];  // 16 KB [key][dim]
    __shared__ __align__(16) unsigned short Vt[2][64][64];  // 16 KB [dim][key]
    __shared__ __align__(16) unsigned char  Mb[2][64][64];  //  8 KB [qrow][key]
    __shared__ __align__(16) unsigned short El[4][16][64];  //  8 KB per-wave E

    const int t    = threadIdx.x;
    const int w    = t >> 6;
    const int lane = t & 63;
    const int l15  = lane & 15;
    const int quad = lane >> 4;
    const int i0   = blockIdx.x * 64;
    const int h    = blockIdx.y;
    const int b    = blockIdx.z;

    bf16x8 qa0, qa1;
    {
        const unsigned short* qp =
            qk + (size_t)(b * NN + i0 + w * 16 + l15) * 2048 + h * HDIM + quad * 8;
        qa0 = *(const bf16x8*)qp;
        qa1 = *(const bf16x8*)(qp + 32);
    }

    bf16x8 onesb;
    {
        short ob = (l15 == 0) ? (short)0x3F80 : (short)0;
#pragma unroll
        for (int j = 0; j < 8; ++j) onesb[j] = ob;
    }

    f32x4 acc[NSEG][5];
#pragma unroll
    for (int m = 0; m < NSEG; ++m)
#pragma unroll
        for (int nt = 0; nt < 5; ++nt) acc[m][nt] = (f32x4){0.f, 0.f, 0.f, 0.f};

    // Async staging: LDS dest is wave-uniform base (+ HW lane*16); the XOR
    // swizzle is applied on the per-lane GLOBAL source address instead.
    auto stage = [&](int bb, int j0) {
        // K tile: 64 keys x 64 dims, 512 granules of 16B
#pragma unroll
        for (int it = 0; it < 2; ++it) {
            int Gb = w * 64 + it * 256;             // wave-uniform granule base
            int G = Gb + lane;
            int row = G >> 3, g = G & 7;            // row=key, g=16B chunk
            const unsigned short* src =
                qk + (size_t)(b * NN + j0 + row) * 2048 + 1024 + h * HDIM + ((g ^ (row & 7)) * 8);
            __builtin_amdgcn_global_load_lds(
                (const __attribute__((address_space(1))) void*)src,
                (__attribute__((address_space(3))) void*)((char*)&Ks[bb][0][0] + Gb * 16), 16, 0, 0);
        }
        // V tile (transposed): 64 dims x 64 keys
#pragma unroll
        for (int it = 0; it < 2; ++it) {
            int Gb = w * 64 + it * 256;
            int G = Gb + lane;
            int row = G >> 3, g = G & 7;            // row=dim, g=8-key chunk
            const unsigned short* src =
                vtg + ((size_t)b * INTER + h * HDIM + row) * NN + j0 + ((g ^ (row & 7)) * 8);
            __builtin_amdgcn_global_load_lds(
                (const __attribute__((address_space(1))) void*)src,
                (__attribute__((address_space(3))) void*)((char*)&Vt[bb][0][0] + Gb * 16), 16, 0, 0);
        }
        // mask tile: 64 rows x 64 bytes, 256 granules (1 per thread)
        {
            int Gb = w * 64;
            int G = Gb + lane;
            int row = G >> 2, g = G & 3;            // row=query, g=16B chunk
            const unsigned char* src =
                mask8 + (size_t)(b * NN + i0 + row) * NN + j0 + ((g ^ (row & 3)) * 16);
            __builtin_amdgcn_global_load_lds(
                (const __attribute__((address_space(1))) void*)src,
                (__attribute__((address_space(3))) void*)((char*)&Mb[bb][0][0] + Gb * 16), 16, 0, 0);
        }
    };

    stage(0, 0);

    for (int jt = 0; jt < NN / 64; ++jt) {
        __syncthreads();                       // drains vmcnt -> buf[jt&1] ready
        if (jt + 1 < NN / 64) stage((jt + 1) & 1, (jt + 1) * 64);
        const int bb = jt & 1;

        // ---- E = exp(scale * Q K^T) -> El (per-wave; same-wave DS ordering) ----
#pragma unroll
        for (int nt = 0; nt < 4; ++nt) {
            f32x4 s = {0.f, 0.f, 0.f, 0.f};
            int rk = nt * 16 + l15, sg = rk & 7;
            bf16x8 kb0 = *(const bf16x8*)&Ks[bb][rk][(quad ^ sg) * 8];
            bf16x8 kb1 = *(const bf16x8*)&Ks[bb][rk][((quad + 4) ^ sg) * 8];
            s = __builtin_amdgcn_mfma_f32_16x16x32_bf16(qa0, kb0, s, 0, 0, 0);
            s = __builtin_amdgcn_mfma_f32_16x16x32_bf16(qa1, kb1, s, 0, 0, 0);
#pragma unroll
            for (int r = 0; r < 4; ++r) {
                float e = __expf(s[r] * 0.03125f);      // scale = INTER^-0.5
                unsigned int u = __builtin_bit_cast(unsigned int, e);
                u += 0x7FFFu + ((u >> 16) & 1u);        // manual RNE to bf16
                int er = quad * 4 + r;
                El[w][er][((2 * nt + (l15 >> 3)) ^ (er & 7)) * 8 + (l15 & 7)] =
                    (unsigned short)(u >> 16);
            }
        }

        // ---- PV: 4 masked A variants x (4 dim tiles + ones tile) ----
#pragma unroll
        for (int ks = 0; ks < 2; ++ks) {
            union { int4 i; bf16x8 v; } ef;
            ef.i = *(const int4*)&El[w][l15][((4 * ks + quad) ^ (l15 & 7)) * 8];
            uint2 sbv = *(const uint2*)((const unsigned char*)&Mb[bb][w * 16 + l15][0]
                            + (((2 * ks + (quad >> 1)) ^ (l15 & 3)) << 4) + ((quad & 1) << 3));
            unsigned int segb[8];
            segb[0] = sbv.x & 0xFF;  segb[1] = (sbv.x >> 8) & 0xFF;
            segb[2] = (sbv.x >> 16) & 0xFF; segb[3] = sbv.x >> 24;
            segb[4] = sbv.y & 0xFF;  segb[5] = (sbv.y >> 8) & 0xFF;
            segb[6] = (sbv.y >> 16) & 0xFF; segb[7] = sbv.y >> 24;
            unsigned int eL[4], eH[4];
#pragma unroll
            for (int d = 0; d < 4; ++d) {
                unsigned int e = ((const unsigned int*)&ef.i)[d];
                eL[d] = e & 0x0000FFFFu;
                eH[d] = e & 0xFFFF0000u;
            }
            bf16x8 vb[4];
#pragma unroll
            for (int nt = 0; nt < 4; ++nt)
                vb[nt] = *(const bf16x8*)&Vt[bb][nt * 16 + l15][((4 * ks + quad) ^ (l15 & 7)) * 8];
#pragma unroll
            for (int m = 0; m < NSEG; ++m) {
                union { int4 i; bf16x8 v; } wm;
#pragma unroll
                for (int d = 0; d < 4; ++d) {
                    unsigned int lo = (segb[2 * d]     == (unsigned)m) ? eL[d] : 0u;
                    unsigned int hi = (segb[2 * d + 1] == (unsigned)m) ? eH[d] : 0u;
                    ((unsigned int*)&wm.i)[d] = lo | hi;
                }
#pragma unroll
                for (int nt = 0; nt < 4; ++nt)
                    acc[m][nt] = __builtin_amdgcn_mfma_f32_16x16x32_bf16(wm.v, vb[nt], acc[m][nt], 0, 0, 0);
                acc[m][4] = __builtin_amdgcn_mfma_f32_16x16x32_bf16(wm.v, onesb, acc[m][4], 0, 0, 0);
            }
        }
    }

    float rres[NSEG][4];
#pragma unroll
    for (int m = 0; m < NSEG; ++m)
#pragma unroll
        for (int r = 0; r < 4; ++r) {
            float sum = __shfl(acc[m][4][r], lane & 48, 64);
            rres[m][r] = (sum > 0.f) ? (1.f / sum) : 0.f;
        }
#pragma unroll
    for (int nt = 0; nt < 4; ++nt)
#pragma unroll
        for (int r = 0; r < 4; ++r) {
            float v = acc[0][nt][r] * rres[0][r] + acc[1][nt][r] * rres[1][r] +
                      acc[2][nt][r] * rres[2][r] + acc[3][nt][r] * rres[3][r];
            ctx[(size_t)(b * NN + i0 + w * 16 + quad * 4 + r) * INTER + h * HDIM + nt * 16 + l15] = v;
        }
}

// ---------------------------------------------------------------------------
extern "C" void kernel_launch(void* const* d_in, const int* in_sizes, int n_in,
                              void* d_out, int out_size, void* d_ws, size_t ws_size,
                              hipStream_t stream) {
    const float* features = (const float*)d_in[0];  // [B,N,DIM] fp32
    const int*   mask     = (const int*)d_in[1];    // [B,N,N]
    const float* W_qkv    = (const float*)d_in[2];  // [DIM, 3*INTER] fp32
    const float* W_out    = (const float*)d_in[3];  // [INTER, DIM] fp32
    float* out = (float*)d_out;                     // [B,N,DIM] fp32

    const int M = BB * NN;  // 4096
    char* ws = (char*)d_ws;
    unsigned short* qk2  = (unsigned short*)ws;                 // bf16 [4096][2048] 16.8 MB
    ws += (size_t)M * 2048 * 2;
    unsigned short* vtg  = (unsigned short*)ws;                 // bf16 [2][1024][2048] 8.4 MB
    ws += (size_t)BB * INTER * NN * 2;
    float* ctx = (float*)ws;                                    // fp32 [4096][1024] 16.8 MB
    ws += (size_t)M * INTER * 4;
    unsigned short* featb = (unsigned short*)ws;                // bf16 [4096][1024] 8.4 MB
    ws += (size_t)M * DIM * 2;
    unsigned short* wqt = (unsigned short*)ws;                  // bf16 [3072][1024] 6.3 MB
    ws += (size_t)QKVW * DIM * 2;
    unsigned char* mask8 = (unsigned char*)ws;                  // int8 [2][2048][2048] 8.4 MB

    dim3 blk(256);

    conv_f32_bf16<<<dim3((M * DIM) / 1024), blk, 0, stream>>>(features, featb);
    conv_mask_i8<<<dim3((BB * NN * NN) / 4096), blk, 0, stream>>>(mask, mask8);
    transp_f32_bf16<<<dim3(QKVW / 64, DIM / 64), blk, 0, stream>>>(W_qkv, wqt, DIM, QKVW);

    // 1) qkv projection: q|k -> qk2, v -> vtg (transposed per head)
    gemm_qkv_mfma<<<dim3(QKVW / 128, M / 128), blk, 0, stream>>>(featb, wqt, qk2, vtg);

    // 2) segment-masked attention -> ctx
    attn_seg_mfma<<<dim3(NN / 64, NHEAD, BB), blk, 0, stream>>>(qk2, vtg, mask8, ctx);

    // 3) out = ctx @ W_out (fp32, exact)
    gemm_fp32<<<dim3(DIM / TILE, M / TILE), blk, 0, stream>>>(
        ctx, W_out, out, M, DIM, INTER);
}